// Round 13
// baseline (223.980 us; speedup 1.0000x reference)
//
#include <hip/hip_runtime.h>

#define SEQ 2048
#define DIM 1024
#define NHEAD 16
#define HDIM 64
#define NTOK 4096   // b*s
#define N3D 3072

typedef __attribute__((ext_vector_type(8))) short bf16x8;
typedef __attribute__((ext_vector_type(4))) float floatx4;
typedef __attribute__((ext_vector_type(4))) unsigned short ushortx4;

__device__ __forceinline__ unsigned short f2bf(float f) {
    unsigned int u = __builtin_bit_cast(unsigned int, f);
    u += 0x7FFFu + ((u >> 16) & 1u);
    return (unsigned short)(u >> 16);
}

// async global->LDS, 16B per lane. LDS dest must be wave-uniform base + lane*16.
__device__ __forceinline__ void async_copy16(const void* g, const void* l) {
    __builtin_amdgcn_global_load_lds(
        (const __attribute__((address_space(1))) unsigned int*)(unsigned long long)g,
        (__attribute__((address_space(3))) unsigned int*)(unsigned int)(unsigned long long)l,
        16, 0, 0);
}

#define MFMA_BF16(a, b, c) __builtin_amdgcn_mfma_f32_16x16x32_bf16((a), (b), (c), 0, 0, 0)

// ---------------------------------------------------------------------------
// Fused prep: weight transposes (fp32->bf16) + LayerNorm + logt bias table.
// Blocks 0..3071: w_qkv T; 3072..4095: w_out T; 4096..8191: LN; 8192..8195:
// logt[i] = beta*log1p(i)*log2(e) - 20 -> GLOBAL (read-only 8KB, L1/L2-hot).
// ---------------------------------------------------------------------------
__global__ __launch_bounds__(256)
void prep_kernel(const float* __restrict__ w_qkv, unsigned short* __restrict__ wqkvT,
                 const float* __restrict__ w_out, unsigned short* __restrict__ woutT,
                 const float* __restrict__ x, const float* __restrict__ gamma,
                 const float* __restrict__ lnb, unsigned short* __restrict__ xn,
                 const float* __restrict__ betap, float* __restrict__ logt_g) {
    const int bid = blockIdx.x;
    const int tid = threadIdx.x;
    if (bid >= 8192) {
        const float betaV = betap[0];
        const float L2E = 1.44269504f;
        int i = (bid - 8192) * 256 + tid;            // 0..1023
        logt_g[i] = betaV * log1pf((float)i) * L2E - 20.0f;
        logt_g[i + 1024] = betaV * log1pf((float)(i + 1024)) * L2E - 20.0f;
        return;
    }
    if (bid < 4096) {
        // ---- transpose + cvt: src [rows(=DIM)][cols] f32 -> dst [cols][rows] bf16
        __shared__ float tile[32][33];
        const float* src; unsigned short* dst; int cols, bx, by;
        if (bid < 3072) { src = w_qkv; dst = wqkvT; cols = N3D; bx = bid % 96; by = bid / 96; }
        else { int t = bid - 3072; src = w_out; dst = woutT; cols = DIM; bx = t & 31; by = t >> 5; }
        const int c0 = bx * 32, r0 = by * 32;
        const int tx = tid & 31, ty = tid >> 5;  // 32 x 8
        for (int i = 0; i < 4; ++i) {
            int r = ty + i * 8;
            tile[r][tx] = src[(size_t)(r0 + r) * cols + c0 + tx];
        }
        __syncthreads();
        for (int i = 0; i < 4; ++i) {
            int rr = ty + i * 8;  // col index in src
            dst[(size_t)(c0 + rr) * DIM + r0 + tx] = f2bf(tile[tx][rr]);
        }
    } else {
        // ---- LayerNorm row: x [4096][1024] f32 -> xn bf16
        const int row = bid - 4096;
        const float* xr = x + (size_t)row * DIM;
        float4 v = ((const float4*)xr)[tid];
        float s = v.x + v.y + v.z + v.w;
        float s2 = v.x * v.x + v.y * v.y + v.z * v.z + v.w * v.w;
        for (int off = 1; off < 64; off <<= 1) {
            s += __shfl_xor(s, off, 64);
            s2 += __shfl_xor(s2, off, 64);
        }
        __shared__ float red[8];
        const int wave = tid >> 6, lane = tid & 63;
        if (lane == 0) { red[wave] = s; red[4 + wave] = s2; }
        __syncthreads();
        s = red[0] + red[1] + red[2] + red[3];
        s2 = red[4] + red[5] + red[6] + red[7];
        const float mu = s * (1.0f / DIM);
        const float var = s2 * (1.0f / DIM) - mu * mu;
        const float rstd = rsqrtf(var + 1e-5f);
        float4 g = ((const float4*)gamma)[tid];
        float4 bb = ((const float4*)lnb)[tid];
        unsigned short* o = xn + (size_t)row * DIM + tid * 4;
        o[0] = f2bf((v.x - mu) * rstd * g.x + bb.x);
        o[1] = f2bf((v.y - mu) * rstd * g.y + bb.y);
        o[2] = f2bf((v.z - mu) * rstd * g.z + bb.z);
        o[3] = f2bf((v.w - mu) * rstd * g.w + bb.w);
    }
}

// ---------------------------------------------------------------------------
// QKV GEMM (FROZEN R6/R12 measured-best: dbuf prefetch, 128x192 tiles,
// 512 wgs = 2 blocks/CU zero-tail, XCD-chunked).
// Scatters q,k -> [b,h,s,hd]; v -> [b,h,hd,s].
// ---------------------------------------------------------------------------
__global__ __launch_bounds__(256)
void qkv_gemm(const unsigned short* __restrict__ A, const unsigned short* __restrict__ Bt,
              const float* __restrict__ bias, unsigned short* __restrict__ qo,
              unsigned short* __restrict__ ko, unsigned short* __restrict__ vTo) {
    __shared__ unsigned short Asm[2][128 * 64];   // 32 KB
    __shared__ unsigned short Bsm[2][192 * 64];   // 48 KB
    const int tid = threadIdx.x;
    const int wave = tid >> 6, lane = tid & 63;
    const int quad = lane >> 4, r16 = lane & 15;
    const int flat = blockIdx.x;
    const int xcd = flat & 7, c = flat >> 3;           // c in [0,64)
    const int mt = (xcd >> 1) * 8 + (c >> 3);          // [0,32)
    const int nt = (xcd & 1) * 8 + (c & 7);            // [0,16)
    const int m0 = mt * 128, n0 = nt * 192;
    const int wm = (wave & 1) * 64, wn = (wave >> 1) * 96;
    floatx4 acc[4][6] = {};
    for (int p = 0; p < 4; ++p) {
        int s = tid + p * 256;
        async_copy16(A + (size_t)(m0 + (s >> 3)) * DIM + ((s & 7) << 3), &Asm[0][s * 8]);
    }
    for (int p = 0; p < 6; ++p) {
        int s = tid + p * 256;
        async_copy16(Bt + (size_t)(n0 + (s >> 3)) * DIM + ((s & 7) << 3), &Bsm[0][s * 8]);
    }
    __syncthreads();
    for (int it = 0; it < 16; ++it) {
        const int cur = it & 1;
        if (it + 1 < 16) {
            const int k1 = (it + 1) * 64;
            for (int p = 0; p < 4; ++p) {
                int s = tid + p * 256;
                async_copy16(A + (size_t)(m0 + (s >> 3)) * DIM + k1 + ((s & 7) << 3),
                             &Asm[cur ^ 1][s * 8]);
            }
            for (int p = 0; p < 6; ++p) {
                int s = tid + p * 256;
                async_copy16(Bt + (size_t)(n0 + (s >> 3)) * DIM + k1 + ((s & 7) << 3),
                             &Bsm[cur ^ 1][s * 8]);
            }
        }
        for (int h = 0; h < 2; ++h) {
            bf16x8 af[4], bfr[6];
            for (int i = 0; i < 4; ++i)
                af[i] = *(const bf16x8*)(&Asm[cur][(wm + i * 16 + r16) * 64 + h * 32 + quad * 8]);
            for (int j = 0; j < 6; ++j)
                bfr[j] = *(const bf16x8*)(&Bsm[cur][(wn + j * 16 + r16) * 64 + h * 32 + quad * 8]);
            for (int i = 0; i < 4; ++i)
                for (int j = 0; j < 6; ++j)
                    acc[i][j] = MFMA_BF16(af[i], bfr[j], acc[i][j]);
        }
        __syncthreads();
    }
    for (int j = 0; j < 6; ++j) {
        int n = n0 + wn + j * 16 + r16;
        float bn = bias[n];
        int part = n >> 10, nn = n & 1023;
        int head = nn >> 6, hdi = nn & 63;
        for (int i = 0; i < 4; ++i) {
            int mbase = m0 + wm + i * 16 + quad * 4;
            int bIdx = mbase >> 11, sIdx = mbase & 2047;
            if (part == 2) {
                ushortx4 pack;
                for (int e = 0; e < 4; ++e) pack[e] = f2bf(acc[i][j][e] + bn);
                *(ushortx4*)(vTo + ((size_t)(bIdx * NHEAD + head) * HDIM + hdi) * SEQ + sIdx) = pack;
            } else {
                unsigned short* dst = (part == 0) ? qo : ko;
                for (int e = 0; e < 4; ++e)
                    dst[((size_t)(bIdx * NHEAD + head) * SEQ + sIdx + e) * HDIM + hdi] =
                        f2bf(acc[i][j][e] + bn);
            }
        }
    }
}

// ---------------------------------------------------------------------------
// Flash attention with log1p distance bias.
// Round-13: QBLK 128 -> 64, 256 threads (4 waves), 1024 blocks = EXACTLY 4
// blocks/CU (16 waves/CU). R12 showed the 512-wg grid itself capped occupancy
// at 2 blocks/CU — LDS cuts couldn't help. Changes: (a) Q fragments loaded
// once from global into registers (no Q LDS, no Q staging barrier); (b) P
// scratch = swizzled [64][64] (slot ^= row&7; rows 128B, 16B-aligned reads,
// ~2-way banks) -> LDS total 16+16+8 = 40960B exactly = 4 blocks/CU;
// (c) barriers now sync 4 waves, and 4 independent blocks/CU hide each
// other's barrier drains. K/V dbuf staging KEPT (R11: load-bearing).
// grid: 1024 1D, XCD-chunked (128 blocks/XCD = 4 bh/XCD for K/V L2 locality).
// ---------------------------------------------------------------------------
__global__ __launch_bounds__(256)
void attn_kernel(const unsigned short* __restrict__ qg, const unsigned short* __restrict__ kg,
                 const unsigned short* __restrict__ vTg, const float* __restrict__ logt,
                 unsigned short* __restrict__ ctx) {
    __shared__ unsigned short QP[64][64];       // wave-private P scratch (swizzled)
    __shared__ unsigned short Kd[2][64 * 64];   // swizzled, rows=key
    __shared__ unsigned short Vd[2][64 * 64];   // swizzled, rows=d (V^T)

    const int tid = threadIdx.x;
    const int wave = tid >> 6, lane = tid & 63;
    const int quad = lane >> 4, r16 = lane & 15;
    // XCD swizzle: 1024 wgs, 128 per XCD -> 4 bh per XCD
    const int flat = blockIdx.x;
    const int swz = (flat & 7) * 128 + (flat >> 3);
    const int bh = swz >> 5, qt = swz & 31;
    const int qBase = qt * 64;
    const float L2E = 1.44269504f;
    const float c1 = 0.125f * L2E;

    // Q fragments: one-time direct global load (registers thereafter)
    const unsigned short* qptr = qg + ((size_t)bh * SEQ + qBase) * HDIM;
    const int qrow = wave * 16 + r16;           // row within this q-tile
    bf16x8 qf0 = *(const bf16x8*)(qptr + qrow * HDIM + quad * 8);
    bf16x8 qf1 = *(const bf16x8*)(qptr + qrow * HDIM + 32 + quad * 8);

    // async-stage K/V chunk 0 into buf 0 (swizzled: colgrp (j&7)^(r&7))
    const unsigned short* kbh = kg + (size_t)bh * SEQ * HDIM;
    const unsigned short* vbh = vTg + (size_t)bh * HDIM * SEQ;
    for (int p = 0; p < 2; ++p) {
        int s = tid + p * 256;
        int sr = s >> 3, scg = (s & 7) ^ (sr & 7);
        async_copy16(kbh + (size_t)sr * HDIM + scg * 8, &Kd[0][s * 8]);
        async_copy16(vbh + (size_t)sr * SEQ + scg * 8, &Vd[0][s * 8]);
    }
    __syncthreads();

    const bf16x8 onesv = {0x3F80, 0x3F80, 0x3F80, 0x3F80, 0x3F80, 0x3F80, 0x3F80, 0x3F80};

    floatx4 o[5] = {};   // o[4] accumulates row sums (ones trick)
    const int qWaveBase = qBase + wave * 16;       // wave-uniform
    const int qrT = qWaveBase + r16;               // this thread's q-row (swapped layout)
    const int rx = r16 & 7;                        // P swizzle key
    unsigned short* prow = &QP[wave * 16 + r16][0];   // 128B row base

    for (int kt0 = 0; kt0 < SEQ; kt0 += 64) {
        const int buf = (kt0 >> 6) & 1;
        if (kt0 + 64 < SEQ) {
            for (int p = 0; p < 2; ++p) {
                int s = tid + p * 256;
                int sr = s >> 3, scg = (s & 7) ^ (sr & 7);
                async_copy16(kbh + (size_t)(kt0 + 64 + sr) * HDIM + scg * 8, &Kd[buf ^ 1][s * 8]);
                async_copy16(vbh + (size_t)sr * SEQ + kt0 + 64 + scg * 8, &Vd[buf ^ 1][s * 8]);
            }
        }

        // QK^T, swapped: D[key][qrow]; lane holds keys keyTile+quad*4+{0..3}, qrow=r16
        floatx4 sc[4];
        __builtin_amdgcn_s_setprio(1);
        for (int ct = 0; ct < 4; ++ct) {
            int rK = ct * 16 + r16;
            const unsigned short* kb = &Kd[buf][rK * 64];
            bf16x8 kf0 = *(const bf16x8*)(kb + ((quad ^ (rK & 7)) << 3));
            bf16x8 kf1 = *(const bf16x8*)(kb + (((quad ^ 4) ^ (rK & 7)) << 3));
            floatx4 z = {0.f, 0.f, 0.f, 0.f};
            z = MFMA_BF16(kf0, qf0, z);   // A=K (k-chunk [0,32)), B=Q
            z = MFMA_BF16(kf1, qf1, z);   // A=K (k-chunk [32,64)), B=Q
            sc[ct] = z;
        }
        __builtin_amdgcn_s_setprio(0);
        // scale + distance bias (log2 domain, fixed -20 offset in table), exp2 -> p.
        for (int ct = 0; ct < 4; ++ct) {
            const int keyTile = kt0 + ct * 16;      // wave-uniform
            const int kbase = keyTile + quad * 4;   // first of this lane's 4 keys
            if (qWaveBase >= keyTile + 16) {        // all queries > all keys
                const float* lp = &logt[qrT - kbase - 3];   // dist = (qrT-kbase) - i
                for (int i = 0; i < 4; ++i)
                    sc[ct][i] = __builtin_amdgcn_exp2f(sc[ct][i] * c1 + lp[3 - i]);
            } else if (keyTile >= qWaveBase + 16) { // all keys > all queries
                const float* lp = &logt[kbase - qrT];       // dist = (kbase-qrT) + i
                for (int i = 0; i < 4; ++i)
                    sc[ct][i] = __builtin_amdgcn_exp2f(sc[ct][i] * c1 + lp[i]);
            } else {                                 // mixed (diagonal tiles)
                for (int i = 0; i < 4; ++i) {
                    int dist = qrT - (kbase + i);
                    dist = dist < 0 ? -dist : dist;
                    sc[ct][i] = __builtin_amdgcn_exp2f(sc[ct][i] * c1 + logt[dist]);
                }
            }
        }
        // P: pack 4 consecutive keys -> one b64 store into swizzled [64][64]
        // scratch. Logical 16B-slot s -> physical s ^ (r16&7) on write AND read.
        for (int ct = 0; ct < 4; ++ct) {
            unsigned int lo, hi;
            asm("v_cvt_pk_bf16_f32 %0, %1, %2" : "=v"(lo) : "v"(sc[ct][0]), "v"(sc[ct][1]));
            asm("v_cvt_pk_bf16_f32 %0, %1, %2" : "=v"(hi) : "v"(sc[ct][2]), "v"(sc[ct][3]));
            uint2 pk; pk.x = lo; pk.y = hi;
            int slot = (2 * ct + (quad >> 1)) ^ rx;
            *(uint2*)((char*)prow + slot * 16 + (quad & 1) * 8) = pk;
        }
        bf16x8 pf0 = *(const bf16x8*)((const char*)prow + ((quad ^ rx) * 16));
        bf16x8 pf1 = *(const bf16x8*)((const char*)prow + (((4 + quad) ^ rx) * 16));
        // PV (+ ones tile for row sums)
        __builtin_amdgcn_s_setprio(1);
        for (int nt = 0; nt < 4; ++nt) {
            int rV = nt * 16 + r16;
            const unsigned short* vb = &Vd[buf][rV * 64];
            bf16x8 vf0 = *(const bf16x8*)(vb + ((quad ^ (rV & 7)) << 3));
            bf16x8 vf1 = *(const bf16x8*)(vb + (((quad ^ 4) ^ (rV & 7)) << 3));
            o[nt] = MFMA_BF16(pf0, vf0, o[nt]);
            o[nt] = MFMA_BF16(pf1, vf1, o[nt]);
        }
        o[4] = MFMA_BF16(pf0, onesv, o[4]);
        o[4] = MFMA_BF16(pf1, onesv, o[4]);
        __builtin_amdgcn_s_setprio(0);

        __syncthreads();
    }

    const int b_ = bh >> 4, h_ = bh & 15;
    for (int i = 0; i < 4; ++i) {
        float inv = 1.0f / o[4][i];
        int qi = qBase + wave * 16 + quad * 4 + i;
        for (int nt = 0; nt < 4; ++nt) {
            int d = nt * 16 + r16;
            ctx[((size_t)(b_ * SEQ + qi)) * DIM + h_ * HDIM + d] = f2bf(o[nt][i] * inv);
        }
    }
}

// ---------------------------------------------------------------------------
// Out projection + bias + residual: out = ctx @ w_out + b_out + x  (fp32 out)
// (FROZEN R6/R12: dbuf prefetch, 128x64 tiles, 512 wgs, XCD swizzle.)
// ---------------------------------------------------------------------------
__global__ __launch_bounds__(256)
void out_gemm(const unsigned short* __restrict__ A, const unsigned short* __restrict__ Bt,
              const float* __restrict__ bias, const float* __restrict__ resid,
              float* __restrict__ out) {
    __shared__ unsigned short Asm[2][128 * 64];   // 32 KB
    __shared__ unsigned short Bsm[2][64 * 64];    // 16 KB
    const int tid = threadIdx.x;
    const int wave = tid >> 6, lane = tid & 63;
    const int quad = lane >> 4, r16 = lane & 15;
    const int flat = blockIdx.y * 16 + blockIdx.x;
    const int swz = (flat & 7) * 64 + (flat >> 3);
    const int m0 = (swz >> 4) * 128, n0 = (swz & 15) * 64;
    const int wm = (wave & 1) * 64, wn = (wave >> 1) * 32;
    floatx4 acc[4][2] = {};
    for (int p = 0; p < 4; ++p) {
        int s = tid + p * 256;
        async_copy16(A + (size_t)(m0 + (s >> 3)) * DIM + ((s & 7) << 3), &Asm[0][s * 8]);
    }
    for (int p = 0; p < 2; ++p) {
        int s = tid + p * 256;
        async_copy16(Bt + (size_t)(n0 + (s >> 3)) * DIM + ((s & 7) << 3), &Bsm[0][s * 8]);
    }
    __syncthreads();
    for (int it = 0; it < 16; ++it) {
        const int cur = it & 1;
        if (it + 1 < 16) {
            const int k1 = (it + 1) * 64;
            for (int p = 0; p < 4; ++p) {
                int s = tid + p * 256;
                async_copy16(A + (size_t)(m0 + (s >> 3)) * DIM + k1 + ((s & 7) << 3),
                             &Asm[cur ^ 1][s * 8]);
            }
            for (int p = 0; p < 2; ++p) {
                int s = tid + p * 256;
                async_copy16(Bt + (size_t)(n0 + (s >> 3)) * DIM + k1 + ((s & 7) << 3),
                             &Bsm[cur ^ 1][s * 8]);
            }
        }
        for (int h = 0; h < 2; ++h) {
            bf16x8 af[4], bfr[2];
            for (int i = 0; i < 4; ++i)
                af[i] = *(const bf16x8*)(&Asm[cur][(wm + i * 16 + r16) * 64 + h * 32 + quad * 8]);
            for (int j = 0; j < 2; ++j)
                bfr[j] = *(const bf16x8*)(&Bsm[cur][(wn + j * 16 + r16) * 64 + h * 32 + quad * 8]);
            for (int i = 0; i < 4; ++i)
                for (int j = 0; j < 2; ++j)
                    acc[i][j] = MFMA_BF16(af[i], bfr[j], acc[i][j]);
        }
        __syncthreads();
    }
    for (int i = 0; i < 4; ++i)
        for (int j = 0; j < 2; ++j)
            for (int e = 0; e < 4; ++e) {
                int m = m0 + wm + i * 16 + quad * 4 + e;
                int n = n0 + wn + j * 16 + r16;
                out[(size_t)m * DIM + n] = acc[i][j][e] + bias[n] + resid[(size_t)m * DIM + n];
            }
}

// ---------------------------------------------------------------------------
extern "C" void kernel_launch(void* const* d_in, const int* in_sizes, int n_in,
                              void* d_out, int out_size, void* d_ws, size_t ws_size,
                              hipStream_t stream) {
    const float* x     = (const float*)d_in[0];
    const float* w_qkv = (const float*)d_in[1];
    const float* b_qkv = (const float*)d_in[2];
    const float* w_out = (const float*)d_in[3];
    const float* b_out = (const float*)d_in[4];
    const float* gamma = (const float*)d_in[5];
    const float* ln_b  = (const float*)d_in[6];
    const float* beta  = (const float*)d_in[7];
    float* out = (float*)d_out;

    char* ws = (char*)d_ws;
    const size_t MB = 1u << 20;
    unsigned short* xn    = (unsigned short*)(ws);            // 8 MB (reused as ctx)
    unsigned short* wqkvT = (unsigned short*)(ws + 8 * MB);   // 6 MB
    unsigned short* woutT = (unsigned short*)(ws + 14 * MB);  // 2 MB
    unsigned short* qb    = (unsigned short*)(ws + 16 * MB);  // 8 MB
    unsigned short* kb    = (unsigned short*)(ws + 24 * MB);  // 8 MB
    unsigned short* vTb   = (unsigned short*)(ws + 32 * MB);  // 8 MB
    float* logt_g         = (float*)(ws + 40 * MB);           // 8 KB
    unsigned short* ctx   = xn;  // xn dead after qkv_gemm; safe alias (stream-ordered)

    prep_kernel<<<8196, 256, 0, stream>>>(w_qkv, wqkvT, w_out, woutT, x, gamma, ln_b, xn,
                                          beta, logt_g);
    qkv_gemm<<<512, 256, 0, stream>>>(xn, wqkvT, b_qkv, qb, kb, vTb);
    attn_kernel<<<1024, 256, 0, stream>>>(qb, kb, vTb, logt_g, ctx);
    out_gemm<<<dim3(16, 32), 256, 0, stream>>>(ctx, woutT, b_out, x, out);
}

// Round 14
// 222.766 us; speedup vs baseline: 1.0055x; 1.0055x over previous
//
#include <hip/hip_runtime.h>

#define SEQ 2048
#define DIM 1024
#define NHEAD 16
#define HDIM 64
#define NTOK 4096   // b*s
#define N3D 3072

typedef __attribute__((ext_vector_type(8))) short bf16x8;
typedef __attribute__((ext_vector_type(4))) float floatx4;
typedef __attribute__((ext_vector_type(4))) unsigned short ushortx4;

__device__ __forceinline__ unsigned short f2bf(float f) {
    unsigned int u = __builtin_bit_cast(unsigned int, f);
    u += 0x7FFFu + ((u >> 16) & 1u);
    return (unsigned short)(u >> 16);
}

// async global->LDS, 16B per lane. LDS dest must be wave-uniform base + lane*16.
__device__ __forceinline__ void async_copy16(const void* g, const void* l) {
    __builtin_amdgcn_global_load_lds(
        (const __attribute__((address_space(1))) unsigned int*)(unsigned long long)g,
        (__attribute__((address_space(3))) unsigned int*)(unsigned int)(unsigned long long)l,
        16, 0, 0);
}

#define MFMA_BF16(a, b, c) __builtin_amdgcn_mfma_f32_16x16x32_bf16((a), (b), (c), 0, 0, 0)

// ---------------------------------------------------------------------------
// Fused prep: weight transposes (fp32->bf16) + LayerNorm + logt bias table.
// Blocks 0..3071: w_qkv T; 3072..4095: w_out T; 4096..8191: LN; 8192..8195:
// logt[i] = beta*log1p(i)*log2(e) - 20 -> GLOBAL (read-only 8KB, L1/L2-hot).
// ---------------------------------------------------------------------------
__global__ __launch_bounds__(256)
void prep_kernel(const float* __restrict__ w_qkv, unsigned short* __restrict__ wqkvT,
                 const float* __restrict__ w_out, unsigned short* __restrict__ woutT,
                 const float* __restrict__ x, const float* __restrict__ gamma,
                 const float* __restrict__ lnb, unsigned short* __restrict__ xn,
                 const float* __restrict__ betap, float* __restrict__ logt_g) {
    const int bid = blockIdx.x;
    const int tid = threadIdx.x;
    if (bid >= 8192) {
        const float betaV = betap[0];
        const float L2E = 1.44269504f;
        int i = (bid - 8192) * 256 + tid;            // 0..1023
        logt_g[i] = betaV * log1pf((float)i) * L2E - 20.0f;
        logt_g[i + 1024] = betaV * log1pf((float)(i + 1024)) * L2E - 20.0f;
        return;
    }
    if (bid < 4096) {
        // ---- transpose + cvt: src [rows(=DIM)][cols] f32 -> dst [cols][rows] bf16
        __shared__ float tile[32][33];
        const float* src; unsigned short* dst; int cols, bx, by;
        if (bid < 3072) { src = w_qkv; dst = wqkvT; cols = N3D; bx = bid % 96; by = bid / 96; }
        else { int t = bid - 3072; src = w_out; dst = woutT; cols = DIM; bx = t & 31; by = t >> 5; }
        const int c0 = bx * 32, r0 = by * 32;
        const int tx = tid & 31, ty = tid >> 5;  // 32 x 8
        for (int i = 0; i < 4; ++i) {
            int r = ty + i * 8;
            tile[r][tx] = src[(size_t)(r0 + r) * cols + c0 + tx];
        }
        __syncthreads();
        for (int i = 0; i < 4; ++i) {
            int rr = ty + i * 8;  // col index in src
            dst[(size_t)(c0 + rr) * DIM + r0 + tx] = f2bf(tile[tx][rr]);
        }
    } else {
        // ---- LayerNorm row: x [4096][1024] f32 -> xn bf16
        const int row = bid - 4096;
        const float* xr = x + (size_t)row * DIM;
        float4 v = ((const float4*)xr)[tid];
        float s = v.x + v.y + v.z + v.w;
        float s2 = v.x * v.x + v.y * v.y + v.z * v.z + v.w * v.w;
        for (int off = 1; off < 64; off <<= 1) {
            s += __shfl_xor(s, off, 64);
            s2 += __shfl_xor(s2, off, 64);
        }
        __shared__ float red[8];
        const int wave = tid >> 6, lane = tid & 63;
        if (lane == 0) { red[wave] = s; red[4 + wave] = s2; }
        __syncthreads();
        s = red[0] + red[1] + red[2] + red[3];
        s2 = red[4] + red[5] + red[6] + red[7];
        const float mu = s * (1.0f / DIM);
        const float var = s2 * (1.0f / DIM) - mu * mu;
        const float rstd = rsqrtf(var + 1e-5f);
        float4 g = ((const float4*)gamma)[tid];
        float4 bb = ((const float4*)lnb)[tid];
        unsigned short* o = xn + (size_t)row * DIM + tid * 4;
        o[0] = f2bf((v.x - mu) * rstd * g.x + bb.x);
        o[1] = f2bf((v.y - mu) * rstd * g.y + bb.y);
        o[2] = f2bf((v.z - mu) * rstd * g.z + bb.z);
        o[3] = f2bf((v.w - mu) * rstd * g.w + bb.w);
    }
}

// ---------------------------------------------------------------------------
// QKV GEMM (FROZEN R6/R12 measured-best: dbuf prefetch, 128x192 tiles,
// 512 wgs = 2 blocks/CU zero-tail, XCD-chunked).
// Scatters q,k -> [b,h,s,hd]; v -> [b,h,hd,s].
// ---------------------------------------------------------------------------
__global__ __launch_bounds__(256)
void qkv_gemm(const unsigned short* __restrict__ A, const unsigned short* __restrict__ Bt,
              const float* __restrict__ bias, unsigned short* __restrict__ qo,
              unsigned short* __restrict__ ko, unsigned short* __restrict__ vTo) {
    __shared__ unsigned short Asm[2][128 * 64];   // 32 KB
    __shared__ unsigned short Bsm[2][192 * 64];   // 48 KB
    const int tid = threadIdx.x;
    const int wave = tid >> 6, lane = tid & 63;
    const int quad = lane >> 4, r16 = lane & 15;
    const int flat = blockIdx.x;
    const int xcd = flat & 7, c = flat >> 3;           // c in [0,64)
    const int mt = (xcd >> 1) * 8 + (c >> 3);          // [0,32)
    const int nt = (xcd & 1) * 8 + (c & 7);            // [0,16)
    const int m0 = mt * 128, n0 = nt * 192;
    const int wm = (wave & 1) * 64, wn = (wave >> 1) * 96;
    floatx4 acc[4][6] = {};
    for (int p = 0; p < 4; ++p) {
        int s = tid + p * 256;
        async_copy16(A + (size_t)(m0 + (s >> 3)) * DIM + ((s & 7) << 3), &Asm[0][s * 8]);
    }
    for (int p = 0; p < 6; ++p) {
        int s = tid + p * 256;
        async_copy16(Bt + (size_t)(n0 + (s >> 3)) * DIM + ((s & 7) << 3), &Bsm[0][s * 8]);
    }
    __syncthreads();
    for (int it = 0; it < 16; ++it) {
        const int cur = it & 1;
        if (it + 1 < 16) {
            const int k1 = (it + 1) * 64;
            for (int p = 0; p < 4; ++p) {
                int s = tid + p * 256;
                async_copy16(A + (size_t)(m0 + (s >> 3)) * DIM + k1 + ((s & 7) << 3),
                             &Asm[cur ^ 1][s * 8]);
            }
            for (int p = 0; p < 6; ++p) {
                int s = tid + p * 256;
                async_copy16(Bt + (size_t)(n0 + (s >> 3)) * DIM + k1 + ((s & 7) << 3),
                             &Bsm[cur ^ 1][s * 8]);
            }
        }
        for (int h = 0; h < 2; ++h) {
            bf16x8 af[4], bfr[6];
            for (int i = 0; i < 4; ++i)
                af[i] = *(const bf16x8*)(&Asm[cur][(wm + i * 16 + r16) * 64 + h * 32 + quad * 8]);
            for (int j = 0; j < 6; ++j)
                bfr[j] = *(const bf16x8*)(&Bsm[cur][(wn + j * 16 + r16) * 64 + h * 32 + quad * 8]);
            for (int i = 0; i < 4; ++i)
                for (int j = 0; j < 6; ++j)
                    acc[i][j] = MFMA_BF16(af[i], bfr[j], acc[i][j]);
        }
        __syncthreads();
    }
    for (int j = 0; j < 6; ++j) {
        int n = n0 + wn + j * 16 + r16;
        float bn = bias[n];
        int part = n >> 10, nn = n & 1023;
        int head = nn >> 6, hdi = nn & 63;
        for (int i = 0; i < 4; ++i) {
            int mbase = m0 + wm + i * 16 + quad * 4;
            int bIdx = mbase >> 11, sIdx = mbase & 2047;
            if (part == 2) {
                ushortx4 pack;
                for (int e = 0; e < 4; ++e) pack[e] = f2bf(acc[i][j][e] + bn);
                *(ushortx4*)(vTo + ((size_t)(bIdx * NHEAD + head) * HDIM + hdi) * SEQ + sIdx) = pack;
            } else {
                unsigned short* dst = (part == 0) ? qo : ko;
                for (int e = 0; e < 4; ++e)
                    dst[((size_t)(bIdx * NHEAD + head) * SEQ + sIdx + e) * HDIM + hdi] =
                        f2bf(acc[i][j][e] + bn);
            }
        }
    }
}

// ---------------------------------------------------------------------------
// Flash attention with log1p distance bias.
// REVERT to R12's measured 66.0 µs version (512 threads, QBLK=128, staged
// K/V dbuf, swapped QK^T, cvt_pk P-pack, logt from global). R13's QBLK=64
// regressed (73.6): halving the tile doubled per-CU staging sweep while
// halving per-block MFMA work. grid: (SEQ/128, B*NHEAD), 512 threads.
// ---------------------------------------------------------------------------
__global__ __launch_bounds__(512)
void attn_kernel(const unsigned short* __restrict__ qg, const unsigned short* __restrict__ kg,
                 const unsigned short* __restrict__ vTg, const float* __restrict__ logt,
                 unsigned short* __restrict__ ctx) {
    __shared__ unsigned short QP[128][72];      // Q tile, then reused as wave-private P
    __shared__ unsigned short Kd[2][64 * 64];   // swizzled, rows=key
    __shared__ unsigned short Vd[2][64 * 64];   // swizzled, rows=d (V^T)

    const int tid = threadIdx.x;
    const int wave = tid >> 6, lane = tid & 63;
    const int quad = lane >> 4, r16 = lane & 15;
    // XCD swizzle: flat dispatch id -> chunked (bh, qt) (nwg=512, 64 per XCD)
    const int flat = blockIdx.y * 16 + blockIdx.x;
    const int swz = (flat & 7) * 64 + (flat >> 3);
    const int bh = swz >> 4, qt = swz & 15;
    const int qBase = qt * 128;
    const float L2E = 1.44269504f;
    const float c1 = 0.125f * L2E;

    // stage Q tile (manual, padded-72 layout)
    const unsigned short* qptr = qg + ((size_t)bh * SEQ + qBase) * HDIM;
    for (int s = tid; s < 1024; s += 512) {
        int r = s >> 3, c8 = (s & 7) << 3;
        *(bf16x8*)(&QP[r][c8]) = *(const bf16x8*)(qptr + r * HDIM + c8);
    }

    // async-stage K/V chunk 0 into buf 0 (swizzled: colgrp (j&7)^(r&7))
    const int sr = tid >> 3;
    const int scg = (tid & 7) ^ (sr & 7);
    const unsigned short* kbh = kg + (size_t)bh * SEQ * HDIM;
    const unsigned short* vbh = vTg + (size_t)bh * HDIM * SEQ;
    async_copy16(kbh + (size_t)sr * HDIM + scg * 8, &Kd[0][tid * 8]);
    async_copy16(vbh + (size_t)sr * SEQ + scg * 8, &Vd[0][tid * 8]);
    __syncthreads();

    // Q fragments (Q region of QP becomes this wave's P scratch afterwards)
    bf16x8 qf0 = *(const bf16x8*)(&QP[wave * 16 + r16][quad * 8]);
    bf16x8 qf1 = *(const bf16x8*)(&QP[wave * 16 + r16][32 + quad * 8]);

    const bf16x8 onesv = {0x3F80, 0x3F80, 0x3F80, 0x3F80, 0x3F80, 0x3F80, 0x3F80, 0x3F80};

    floatx4 o[5] = {};   // o[4] accumulates row sums (ones trick)
    const int qWaveBase = qBase + wave * 16;       // wave-uniform
    const int qrT = qWaveBase + r16;               // this thread's q-row (swapped layout)

    for (int kt0 = 0; kt0 < SEQ; kt0 += 64) {
        const int buf = (kt0 >> 6) & 1;
        if (kt0 + 64 < SEQ) {
            async_copy16(kbh + (size_t)(kt0 + 64 + sr) * HDIM + scg * 8, &Kd[buf ^ 1][tid * 8]);
            async_copy16(vbh + (size_t)sr * SEQ + kt0 + 64 + scg * 8, &Vd[buf ^ 1][tid * 8]);
        }

        // QK^T, swapped: D[key][qrow]; lane holds keys keyTile+quad*4+{0..3}, qrow=r16
        floatx4 sc[4];
        __builtin_amdgcn_s_setprio(1);
        for (int ct = 0; ct < 4; ++ct) {
            int rK = ct * 16 + r16;
            const unsigned short* kb = &Kd[buf][rK * 64];
            bf16x8 kf0 = *(const bf16x8*)(kb + ((quad ^ (rK & 7)) << 3));
            bf16x8 kf1 = *(const bf16x8*)(kb + (((quad ^ 4) ^ (rK & 7)) << 3));
            floatx4 z = {0.f, 0.f, 0.f, 0.f};
            z = MFMA_BF16(kf0, qf0, z);   // A=K (k-chunk [0,32)), B=Q
            z = MFMA_BF16(kf1, qf1, z);   // A=K (k-chunk [32,64)), B=Q
            sc[ct] = z;
        }
        __builtin_amdgcn_s_setprio(0);
        // scale + distance bias (log2 domain, fixed -20 offset in table), exp2 -> p.
        for (int ct = 0; ct < 4; ++ct) {
            const int keyTile = kt0 + ct * 16;      // wave-uniform
            const int kbase = keyTile + quad * 4;   // first of this lane's 4 keys
            if (qWaveBase >= keyTile + 16) {        // all queries > all keys
                const float* lp = &logt[qrT - kbase - 3];   // dist = (qrT-kbase) - i
                for (int i = 0; i < 4; ++i)
                    sc[ct][i] = __builtin_amdgcn_exp2f(sc[ct][i] * c1 + lp[3 - i]);
            } else if (keyTile >= qWaveBase + 16) { // all keys > all queries
                const float* lp = &logt[kbase - qrT];       // dist = (kbase-qrT) + i
                for (int i = 0; i < 4; ++i)
                    sc[ct][i] = __builtin_amdgcn_exp2f(sc[ct][i] * c1 + lp[i]);
            } else {                                 // mixed (diagonal tiles)
                for (int i = 0; i < 4; ++i) {
                    int dist = qrT - (kbase + i);
                    dist = dist < 0 ? -dist : dist;
                    sc[ct][i] = __builtin_amdgcn_exp2f(sc[ct][i] * c1 + logt[dist]);
                }
            }
        }
        // P: pack 4 consecutive keys (RNE via v_cvt_pk_bf16_f32) -> one b64 store.
        // Row = this lane's q-row (wave-private; no barrier needed before read-back).
        {
            unsigned short* prow = &QP[wave * 16 + r16][0];
            for (int ct = 0; ct < 4; ++ct) {
                unsigned int lo, hi;
                asm("v_cvt_pk_bf16_f32 %0, %1, %2" : "=v"(lo) : "v"(sc[ct][0]), "v"(sc[ct][1]));
                asm("v_cvt_pk_bf16_f32 %0, %1, %2" : "=v"(hi) : "v"(sc[ct][2]), "v"(sc[ct][3]));
                uint2 pk; pk.x = lo; pk.y = hi;
                *(uint2*)(prow + ct * 16 + quad * 4) = pk;   // 8B-aligned (144B rows)
            }
        }
        bf16x8 pf0 = *(const bf16x8*)(&QP[wave * 16 + r16][quad * 8]);
        bf16x8 pf1 = *(const bf16x8*)(&QP[wave * 16 + r16][32 + quad * 8]);
        // PV (+ ones tile for row sums)
        __builtin_amdgcn_s_setprio(1);
        for (int nt = 0; nt < 4; ++nt) {
            int rV = nt * 16 + r16;
            const unsigned short* vb = &Vd[buf][rV * 64];
            bf16x8 vf0 = *(const bf16x8*)(vb + ((quad ^ (rV & 7)) << 3));
            bf16x8 vf1 = *(const bf16x8*)(vb + (((quad ^ 4) ^ (rV & 7)) << 3));
            o[nt] = MFMA_BF16(pf0, vf0, o[nt]);
            o[nt] = MFMA_BF16(pf1, vf1, o[nt]);
        }
        o[4] = MFMA_BF16(pf0, onesv, o[4]);
        o[4] = MFMA_BF16(pf1, onesv, o[4]);
        __builtin_amdgcn_s_setprio(0);

        __syncthreads();
    }

    const int b_ = bh >> 4, h_ = bh & 15;
    for (int i = 0; i < 4; ++i) {
        float inv = 1.0f / o[4][i];
        int qi = qBase + wave * 16 + quad * 4 + i;
        for (int nt = 0; nt < 4; ++nt) {
            int d = nt * 16 + r16;
            ctx[((size_t)(b_ * SEQ + qi)) * DIM + h_ * HDIM + d] = f2bf(o[nt][i] * inv);
        }
    }
}

// ---------------------------------------------------------------------------
// Out projection + bias + residual: out = ctx @ w_out + b_out + x  (fp32 out)
// Round-14: 128x64 -> 128x128 tiles. 256 wgs = EXACTLY 1 block/CU, zero tail.
// 32 MFMA/iter/wave (2x prev) against the same barrier+staging overhead.
// XCD chunk: 32 tiles/XCD = 4 m-tiles x 8 n -> A-panel 1MB + B 2MB L2-local.
// dbuf prefetch kept. LDS 64 KB.
// ---------------------------------------------------------------------------
__global__ __launch_bounds__(256)
void out_gemm(const unsigned short* __restrict__ A, const unsigned short* __restrict__ Bt,
              const float* __restrict__ bias, const float* __restrict__ resid,
              float* __restrict__ out) {
    __shared__ unsigned short Asm[2][128 * 64];   // 32 KB
    __shared__ unsigned short Bsm[2][128 * 64];   // 32 KB
    const int tid = threadIdx.x;
    const int wave = tid >> 6, lane = tid & 63;
    const int quad = lane >> 4, r16 = lane & 15;
    // XCD chunk: 256 wgs, 32 per XCD = 4 m-tiles x 8 n-tiles
    const int flat = blockIdx.x;
    const int xcd = flat & 7, c = flat >> 3;       // c in [0,32)
    const int m0 = (xcd * 4 + (c >> 3)) * 128;     // mt in [0,32)
    const int n0 = (c & 7) * 128;                  // nt in [0,8)
    const int wm = (wave & 1) * 64, wn = (wave >> 1) * 64;
    floatx4 acc[4][4] = {};
    // prologue: stage K-tile 0 into buf 0
    for (int p = 0; p < 4; ++p) {
        int s = tid + p * 256;
        async_copy16(A + (size_t)(m0 + (s >> 3)) * DIM + ((s & 7) << 3), &Asm[0][s * 8]);
        async_copy16(Bt + (size_t)(n0 + (s >> 3)) * DIM + ((s & 7) << 3), &Bsm[0][s * 8]);
    }
    __syncthreads();
    for (int it = 0; it < 16; ++it) {
        const int cur = it & 1;
        if (it + 1 < 16) {
            const int k1 = (it + 1) * 64;
            for (int p = 0; p < 4; ++p) {
                int s = tid + p * 256;
                async_copy16(A + (size_t)(m0 + (s >> 3)) * DIM + k1 + ((s & 7) << 3),
                             &Asm[cur ^ 1][s * 8]);
                async_copy16(Bt + (size_t)(n0 + (s >> 3)) * DIM + k1 + ((s & 7) << 3),
                             &Bsm[cur ^ 1][s * 8]);
            }
        }
        for (int h = 0; h < 2; ++h) {
            bf16x8 af[4], bfr[4];
            for (int i = 0; i < 4; ++i)
                af[i] = *(const bf16x8*)(&Asm[cur][(wm + i * 16 + r16) * 64 + h * 32 + quad * 8]);
            for (int j = 0; j < 4; ++j)
                bfr[j] = *(const bf16x8*)(&Bsm[cur][(wn + j * 16 + r16) * 64 + h * 32 + quad * 8]);
            for (int i = 0; i < 4; ++i)
                for (int j = 0; j < 4; ++j)
                    acc[i][j] = MFMA_BF16(af[i], bfr[j], acc[i][j]);
        }
        __syncthreads();
    }
    for (int i = 0; i < 4; ++i)
        for (int j = 0; j < 4; ++j)
            for (int e = 0; e < 4; ++e) {
                int m = m0 + wm + i * 16 + quad * 4 + e;
                int n = n0 + wn + j * 16 + r16;
                out[(size_t)m * DIM + n] = acc[i][j][e] + bias[n] + resid[(size_t)m * DIM + n];
            }
}

// ---------------------------------------------------------------------------
extern "C" void kernel_launch(void* const* d_in, const int* in_sizes, int n_in,
                              void* d_out, int out_size, void* d_ws, size_t ws_size,
                              hipStream_t stream) {
    const float* x     = (const float*)d_in[0];
    const float* w_qkv = (const float*)d_in[1];
    const float* b_qkv = (const float*)d_in[2];
    const float* w_out = (const float*)d_in[3];
    const float* b_out = (const float*)d_in[4];
    const float* gamma = (const float*)d_in[5];
    const float* ln_b  = (const float*)d_in[6];
    const float* beta  = (const float*)d_in[7];
    float* out = (float*)d_out;

    char* ws = (char*)d_ws;
    const size_t MB = 1u << 20;
    unsigned short* xn    = (unsigned short*)(ws);            // 8 MB (reused as ctx)
    unsigned short* wqkvT = (unsigned short*)(ws + 8 * MB);   // 6 MB
    unsigned short* woutT = (unsigned short*)(ws + 14 * MB);  // 2 MB
    unsigned short* qb    = (unsigned short*)(ws + 16 * MB);  // 8 MB
    unsigned short* kb    = (unsigned short*)(ws + 24 * MB);  // 8 MB
    unsigned short* vTb   = (unsigned short*)(ws + 32 * MB);  // 8 MB
    float* logt_g         = (float*)(ws + 40 * MB);           // 8 KB
    unsigned short* ctx   = xn;  // xn dead after qkv_gemm; safe alias (stream-ordered)

    prep_kernel<<<8196, 256, 0, stream>>>(w_qkv, wqkvT, w_out, woutT, x, gamma, ln_b, xn,
                                          beta, logt_g);
    qkv_gemm<<<512, 256, 0, stream>>>(xn, wqkvT, b_qkv, qb, kb, vTb);
    attn_kernel<<<dim3(SEQ / 128, 32), 512, 0, stream>>>(qb, kb, vTb, logt_g, ctx);
    out_gemm<<<256, 256, 0, stream>>>(ctx, woutT, b_out, x, out);
}

// Round 15
// 202.982 us; speedup vs baseline: 1.1034x; 1.0975x over previous
//
#include <hip/hip_runtime.h>

#define SEQ 2048
#define DIM 1024
#define NHEAD 16
#define HDIM 64
#define NTOK 4096   // b*s
#define N3D 3072

typedef __attribute__((ext_vector_type(8))) short bf16x8;
typedef __attribute__((ext_vector_type(4))) float floatx4;
typedef __attribute__((ext_vector_type(4))) unsigned short ushortx4;

__device__ __forceinline__ unsigned short f2bf(float f) {
    unsigned int u = __builtin_bit_cast(unsigned int, f);
    u += 0x7FFFu + ((u >> 16) & 1u);
    return (unsigned short)(u >> 16);
}

// async global->LDS, 16B per lane. LDS dest must be wave-uniform base + lane*16.
__device__ __forceinline__ void async_copy16(const void* g, const void* l) {
    __builtin_amdgcn_global_load_lds(
        (const __attribute__((address_space(1))) unsigned int*)(unsigned long long)g,
        (__attribute__((address_space(3))) unsigned int*)(unsigned int)(unsigned long long)l,
        16, 0, 0);
}

#define MFMA_BF16(a, b, c) __builtin_amdgcn_mfma_f32_16x16x32_bf16((a), (b), (c), 0, 0, 0)

// ---------------------------------------------------------------------------
// Fused prep: weight transposes (fp32->bf16) + LayerNorm + logt bias table.
// Blocks 0..3071: w_qkv T; 3072..4095: w_out T; 4096..8191: LN; 8192..8195:
// logt[i] = beta*log1p(i)*log2(e) - 20 -> GLOBAL (read-only 8KB, L1/L2-hot).
// ---------------------------------------------------------------------------
__global__ __launch_bounds__(256)
void prep_kernel(const float* __restrict__ w_qkv, unsigned short* __restrict__ wqkvT,
                 const float* __restrict__ w_out, unsigned short* __restrict__ woutT,
                 const float* __restrict__ x, const float* __restrict__ gamma,
                 const float* __restrict__ lnb, unsigned short* __restrict__ xn,
                 const float* __restrict__ betap, float* __restrict__ logt_g) {
    const int bid = blockIdx.x;
    const int tid = threadIdx.x;
    if (bid >= 8192) {
        const float betaV = betap[0];
        const float L2E = 1.44269504f;
        int i = (bid - 8192) * 256 + tid;            // 0..1023
        logt_g[i] = betaV * log1pf((float)i) * L2E - 20.0f;
        logt_g[i + 1024] = betaV * log1pf((float)(i + 1024)) * L2E - 20.0f;
        return;
    }
    if (bid < 4096) {
        // ---- transpose + cvt: src [rows(=DIM)][cols] f32 -> dst [cols][rows] bf16
        __shared__ float tile[32][33];
        const float* src; unsigned short* dst; int cols, bx, by;
        if (bid < 3072) { src = w_qkv; dst = wqkvT; cols = N3D; bx = bid % 96; by = bid / 96; }
        else { int t = bid - 3072; src = w_out; dst = woutT; cols = DIM; bx = t & 31; by = t >> 5; }
        const int c0 = bx * 32, r0 = by * 32;
        const int tx = tid & 31, ty = tid >> 5;  // 32 x 8
        for (int i = 0; i < 4; ++i) {
            int r = ty + i * 8;
            tile[r][tx] = src[(size_t)(r0 + r) * cols + c0 + tx];
        }
        __syncthreads();
        for (int i = 0; i < 4; ++i) {
            int rr = ty + i * 8;  // col index in src
            dst[(size_t)(c0 + rr) * DIM + r0 + tx] = f2bf(tile[tx][rr]);
        }
    } else {
        // ---- LayerNorm row: x [4096][1024] f32 -> xn bf16
        const int row = bid - 4096;
        const float* xr = x + (size_t)row * DIM;
        float4 v = ((const float4*)xr)[tid];
        float s = v.x + v.y + v.z + v.w;
        float s2 = v.x * v.x + v.y * v.y + v.z * v.z + v.w * v.w;
        for (int off = 1; off < 64; off <<= 1) {
            s += __shfl_xor(s, off, 64);
            s2 += __shfl_xor(s2, off, 64);
        }
        __shared__ float red[8];
        const int wave = tid >> 6, lane = tid & 63;
        if (lane == 0) { red[wave] = s; red[4 + wave] = s2; }
        __syncthreads();
        s = red[0] + red[1] + red[2] + red[3];
        s2 = red[4] + red[5] + red[6] + red[7];
        const float mu = s * (1.0f / DIM);
        const float var = s2 * (1.0f / DIM) - mu * mu;
        const float rstd = rsqrtf(var + 1e-5f);
        float4 g = ((const float4*)gamma)[tid];
        float4 bb = ((const float4*)lnb)[tid];
        unsigned short* o = xn + (size_t)row * DIM + tid * 4;
        o[0] = f2bf((v.x - mu) * rstd * g.x + bb.x);
        o[1] = f2bf((v.y - mu) * rstd * g.y + bb.y);
        o[2] = f2bf((v.z - mu) * rstd * g.z + bb.z);
        o[3] = f2bf((v.w - mu) * rstd * g.w + bb.w);
    }
}

// ---------------------------------------------------------------------------
// QKV GEMM. Round-15: scale the verified 2-phase dbuf skeleton to 256x192,
// BK=64, 8 waves (512 thr). Rationale: guide's m230-V0 reference — SAME sync
// structure (2-phase dbuf, K=1024) at 256-tile/8-wave — measures 682 TF vs
// our 380 at 128x192/4-wave. Doubles per-wave MFMA per K-step (48 vs 24)
// against the same barrier+staging cost; 256 wgs = EXACTLY 1 block/CU, zero
// tail; LDS 112 KB. Parameter change only — sync skeleton inherited.
// Scatters q,k -> [b,h,s,hd]; v -> [b,h,hd,s].
// ---------------------------------------------------------------------------
__global__ __launch_bounds__(512)
void qkv_gemm(const unsigned short* __restrict__ A, const unsigned short* __restrict__ Bt,
              const float* __restrict__ bias, unsigned short* __restrict__ qo,
              unsigned short* __restrict__ ko, unsigned short* __restrict__ vTo) {
    __shared__ unsigned short Asm[2][256 * 64];   // 64 KB
    __shared__ unsigned short Bsm[2][192 * 64];   // 48 KB
    const int tid = threadIdx.x;
    const int wave = tid >> 6, lane = tid & 63;
    const int quad = lane >> 4, r16 = lane & 15;
    // XCD chunk: 256 wgs, 32/XCD = 4 m-tiles x 8 n-tiles
    const int flat = blockIdx.x;
    const int xcd = flat & 7, c = flat >> 3;           // c in [0,32)
    const int mt = (xcd >> 1) * 4 + (c >> 3);          // [0,16)
    const int nt = (xcd & 1) * 8 + (c & 7);            // [0,16)
    const int m0 = mt * 256, n0 = nt * 192;
    const int wm = (wave & 1) * 128, wn = (wave >> 1) * 48;
    floatx4 acc[8][3] = {};
    // prologue: stage K-tile 0 into buf 0
    for (int p = 0; p < 4; ++p) {
        int s = tid + p * 512;          // [0,2048): 256 rows x 8 slots
        async_copy16(A + (size_t)(m0 + (s >> 3)) * DIM + ((s & 7) << 3), &Asm[0][s * 8]);
    }
    for (int p = 0; p < 3; ++p) {
        int s = tid + p * 512;          // [0,1536): 192 rows x 8 slots
        async_copy16(Bt + (size_t)(n0 + (s >> 3)) * DIM + ((s & 7) << 3), &Bsm[0][s * 8]);
    }
    __syncthreads();
    for (int it = 0; it < 16; ++it) {
        const int cur = it & 1;
        if (it + 1 < 16) {   // prefetch next K-tile into the other buffer
            const int k1 = (it + 1) * 64;
            for (int p = 0; p < 4; ++p) {
                int s = tid + p * 512;
                async_copy16(A + (size_t)(m0 + (s >> 3)) * DIM + k1 + ((s & 7) << 3),
                             &Asm[cur ^ 1][s * 8]);
            }
            for (int p = 0; p < 3; ++p) {
                int s = tid + p * 512;
                async_copy16(Bt + (size_t)(n0 + (s >> 3)) * DIM + k1 + ((s & 7) << 3),
                             &Bsm[cur ^ 1][s * 8]);
            }
        }
        for (int h = 0; h < 2; ++h) {
            bf16x8 af[8], bfr[3];
            for (int i = 0; i < 8; ++i)
                af[i] = *(const bf16x8*)(&Asm[cur][(wm + i * 16 + r16) * 64 + h * 32 + quad * 8]);
            for (int j = 0; j < 3; ++j)
                bfr[j] = *(const bf16x8*)(&Bsm[cur][(wn + j * 16 + r16) * 64 + h * 32 + quad * 8]);
            for (int i = 0; i < 8; ++i)
                for (int j = 0; j < 3; ++j)
                    acc[i][j] = MFMA_BF16(af[i], bfr[j], acc[i][j]);
        }
        __syncthreads();
    }
    for (int j = 0; j < 3; ++j) {
        int n = n0 + wn + j * 16 + r16;
        float bn = bias[n];
        int part = n >> 10, nn = n & 1023;
        int head = nn >> 6, hdi = nn & 63;
        for (int i = 0; i < 8; ++i) {
            int mbase = m0 + wm + i * 16 + quad * 4;
            int bIdx = mbase >> 11, sIdx = mbase & 2047;
            if (part == 2) {
                ushortx4 pack;
                for (int e = 0; e < 4; ++e) pack[e] = f2bf(acc[i][j][e] + bn);
                *(ushortx4*)(vTo + ((size_t)(bIdx * NHEAD + head) * HDIM + hdi) * SEQ + sIdx) = pack;
            } else {
                unsigned short* dst = (part == 0) ? qo : ko;
                for (int e = 0; e < 4; ++e)
                    dst[((size_t)(bIdx * NHEAD + head) * SEQ + sIdx + e) * HDIM + hdi] =
                        f2bf(acc[i][j][e] + bn);
            }
        }
    }
}

// ---------------------------------------------------------------------------
// Flash attention with log1p distance bias (FROZEN R12 measured 66.0 µs:
// 512 threads, QBLK=128, staged K/V dbuf, swapped QK^T, cvt_pk P-pack,
// logt from global). grid: (SEQ/128, B*NHEAD), 512 threads.
// ---------------------------------------------------------------------------
__global__ __launch_bounds__(512)
void attn_kernel(const unsigned short* __restrict__ qg, const unsigned short* __restrict__ kg,
                 const unsigned short* __restrict__ vTg, const float* __restrict__ logt,
                 unsigned short* __restrict__ ctx) {
    __shared__ unsigned short QP[128][72];      // Q tile, then reused as wave-private P
    __shared__ unsigned short Kd[2][64 * 64];   // swizzled, rows=key
    __shared__ unsigned short Vd[2][64 * 64];   // swizzled, rows=d (V^T)

    const int tid = threadIdx.x;
    const int wave = tid >> 6, lane = tid & 63;
    const int quad = lane >> 4, r16 = lane & 15;
    // XCD swizzle: flat dispatch id -> chunked (bh, qt) (nwg=512, 64 per XCD)
    const int flat = blockIdx.y * 16 + blockIdx.x;
    const int swz = (flat & 7) * 64 + (flat >> 3);
    const int bh = swz >> 4, qt = swz & 15;
    const int qBase = qt * 128;
    const float L2E = 1.44269504f;
    const float c1 = 0.125f * L2E;

    // stage Q tile (manual, padded-72 layout)
    const unsigned short* qptr = qg + ((size_t)bh * SEQ + qBase) * HDIM;
    for (int s = tid; s < 1024; s += 512) {
        int r = s >> 3, c8 = (s & 7) << 3;
        *(bf16x8*)(&QP[r][c8]) = *(const bf16x8*)(qptr + r * HDIM + c8);
    }

    // async-stage K/V chunk 0 into buf 0 (swizzled: colgrp (j&7)^(r&7))
    const int sr = tid >> 3;
    const int scg = (tid & 7) ^ (sr & 7);
    const unsigned short* kbh = kg + (size_t)bh * SEQ * HDIM;
    const unsigned short* vbh = vTg + (size_t)bh * HDIM * SEQ;
    async_copy16(kbh + (size_t)sr * HDIM + scg * 8, &Kd[0][tid * 8]);
    async_copy16(vbh + (size_t)sr * SEQ + scg * 8, &Vd[0][tid * 8]);
    __syncthreads();

    // Q fragments (Q region of QP becomes this wave's P scratch afterwards)
    bf16x8 qf0 = *(const bf16x8*)(&QP[wave * 16 + r16][quad * 8]);
    bf16x8 qf1 = *(const bf16x8*)(&QP[wave * 16 + r16][32 + quad * 8]);

    const bf16x8 onesv = {0x3F80, 0x3F80, 0x3F80, 0x3F80, 0x3F80, 0x3F80, 0x3F80, 0x3F80};

    floatx4 o[5] = {};   // o[4] accumulates row sums (ones trick)
    const int qWaveBase = qBase + wave * 16;       // wave-uniform
    const int qrT = qWaveBase + r16;               // this thread's q-row (swapped layout)

    for (int kt0 = 0; kt0 < SEQ; kt0 += 64) {
        const int buf = (kt0 >> 6) & 1;
        if (kt0 + 64 < SEQ) {
            async_copy16(kbh + (size_t)(kt0 + 64 + sr) * HDIM + scg * 8, &Kd[buf ^ 1][tid * 8]);
            async_copy16(vbh + (size_t)sr * SEQ + kt0 + 64 + scg * 8, &Vd[buf ^ 1][tid * 8]);
        }

        // QK^T, swapped: D[key][qrow]; lane holds keys keyTile+quad*4+{0..3}, qrow=r16
        floatx4 sc[4];
        __builtin_amdgcn_s_setprio(1);
        for (int ct = 0; ct < 4; ++ct) {
            int rK = ct * 16 + r16;
            const unsigned short* kb = &Kd[buf][rK * 64];
            bf16x8 kf0 = *(const bf16x8*)(kb + ((quad ^ (rK & 7)) << 3));
            bf16x8 kf1 = *(const bf16x8*)(kb + (((quad ^ 4) ^ (rK & 7)) << 3));
            floatx4 z = {0.f, 0.f, 0.f, 0.f};
            z = MFMA_BF16(kf0, qf0, z);   // A=K (k-chunk [0,32)), B=Q
            z = MFMA_BF16(kf1, qf1, z);   // A=K (k-chunk [32,64)), B=Q
            sc[ct] = z;
        }
        __builtin_amdgcn_s_setprio(0);
        // scale + distance bias (log2 domain, fixed -20 offset in table), exp2 -> p.
        for (int ct = 0; ct < 4; ++ct) {
            const int keyTile = kt0 + ct * 16;      // wave-uniform
            const int kbase = keyTile + quad * 4;   // first of this lane's 4 keys
            if (qWaveBase >= keyTile + 16) {        // all queries > all keys
                const float* lp = &logt[qrT - kbase - 3];   // dist = (qrT-kbase) - i
                for (int i = 0; i < 4; ++i)
                    sc[ct][i] = __builtin_amdgcn_exp2f(sc[ct][i] * c1 + lp[3 - i]);
            } else if (keyTile >= qWaveBase + 16) { // all keys > all queries
                const float* lp = &logt[kbase - qrT];       // dist = (kbase-qrT) + i
                for (int i = 0; i < 4; ++i)
                    sc[ct][i] = __builtin_amdgcn_exp2f(sc[ct][i] * c1 + lp[i]);
            } else {                                 // mixed (diagonal tiles)
                for (int i = 0; i < 4; ++i) {
                    int dist = qrT - (kbase + i);
                    dist = dist < 0 ? -dist : dist;
                    sc[ct][i] = __builtin_amdgcn_exp2f(sc[ct][i] * c1 + logt[dist]);
                }
            }
        }
        // P: pack 4 consecutive keys (RNE via v_cvt_pk_bf16_f32) -> one b64 store.
        {
            unsigned short* prow = &QP[wave * 16 + r16][0];
            for (int ct = 0; ct < 4; ++ct) {
                unsigned int lo, hi;
                asm("v_cvt_pk_bf16_f32 %0, %1, %2" : "=v"(lo) : "v"(sc[ct][0]), "v"(sc[ct][1]));
                asm("v_cvt_pk_bf16_f32 %0, %1, %2" : "=v"(hi) : "v"(sc[ct][2]), "v"(sc[ct][3]));
                uint2 pk; pk.x = lo; pk.y = hi;
                *(uint2*)(prow + ct * 16 + quad * 4) = pk;   // 8B-aligned (144B rows)
            }
        }
        bf16x8 pf0 = *(const bf16x8*)(&QP[wave * 16 + r16][quad * 8]);
        bf16x8 pf1 = *(const bf16x8*)(&QP[wave * 16 + r16][32 + quad * 8]);
        // PV (+ ones tile for row sums)
        __builtin_amdgcn_s_setprio(1);
        for (int nt = 0; nt < 4; ++nt) {
            int rV = nt * 16 + r16;
            const unsigned short* vb = &Vd[buf][rV * 64];
            bf16x8 vf0 = *(const bf16x8*)(vb + ((quad ^ (rV & 7)) << 3));
            bf16x8 vf1 = *(const bf16x8*)(vb + (((quad ^ 4) ^ (rV & 7)) << 3));
            o[nt] = MFMA_BF16(pf0, vf0, o[nt]);
            o[nt] = MFMA_BF16(pf1, vf1, o[nt]);
        }
        o[4] = MFMA_BF16(pf0, onesv, o[4]);
        o[4] = MFMA_BF16(pf1, onesv, o[4]);
        __builtin_amdgcn_s_setprio(0);

        __syncthreads();
    }

    const int b_ = bh >> 4, h_ = bh & 15;
    for (int i = 0; i < 4; ++i) {
        float inv = 1.0f / o[4][i];
        int qi = qBase + wave * 16 + quad * 4 + i;
        for (int nt = 0; nt < 4; ++nt) {
            int d = nt * 16 + r16;
            ctx[((size_t)(b_ * SEQ + qi)) * DIM + h_ * HDIM + d] = f2bf(o[nt][i] * inv);
        }
    }
}

// ---------------------------------------------------------------------------
// Out projection + bias + residual: out = ctx @ w_out + b_out + x  (fp32 out)
// REVERT to R6 measured-best: dbuf prefetch, 128x64 tiles, 512 wgs = 2
// blocks/CU (R14's 128x128 @ 1 block/CU was neutral-to-negative — no
// co-resident block to hide dbuf latency). XCD-chunked swizzle.
// ---------------------------------------------------------------------------
__global__ __launch_bounds__(256)
void out_gemm(const unsigned short* __restrict__ A, const unsigned short* __restrict__ Bt,
              const float* __restrict__ bias, const float* __restrict__ resid,
              float* __restrict__ out) {
    __shared__ unsigned short Asm[2][128 * 64];   // 32 KB
    __shared__ unsigned short Bsm[2][64 * 64];    // 16 KB
    const int tid = threadIdx.x;
    const int wave = tid >> 6, lane = tid & 63;
    const int quad = lane >> 4, r16 = lane & 15;
    const int flat = blockIdx.y * 16 + blockIdx.x;
    const int swz = (flat & 7) * 64 + (flat >> 3);
    const int m0 = (swz >> 4) * 128, n0 = (swz & 15) * 64;
    const int wm = (wave & 1) * 64, wn = (wave >> 1) * 32;
    floatx4 acc[4][2] = {};
    for (int p = 0; p < 4; ++p) {
        int s = tid + p * 256;
        async_copy16(A + (size_t)(m0 + (s >> 3)) * DIM + ((s & 7) << 3), &Asm[0][s * 8]);
    }
    for (int p = 0; p < 2; ++p) {
        int s = tid + p * 256;
        async_copy16(Bt + (size_t)(n0 + (s >> 3)) * DIM + ((s & 7) << 3), &Bsm[0][s * 8]);
    }
    __syncthreads();
    for (int it = 0; it < 16; ++it) {
        const int cur = it & 1;
        if (it + 1 < 16) {
            const int k1 = (it + 1) * 64;
            for (int p = 0; p < 4; ++p) {
                int s = tid + p * 256;
                async_copy16(A + (size_t)(m0 + (s >> 3)) * DIM + k1 + ((s & 7) << 3),
                             &Asm[cur ^ 1][s * 8]);
            }
            for (int p = 0; p < 2; ++p) {
                int s = tid + p * 256;
                async_copy16(Bt + (size_t)(n0 + (s >> 3)) * DIM + k1 + ((s & 7) << 3),
                             &Bsm[cur ^ 1][s * 8]);
            }
        }
        for (int h = 0; h < 2; ++h) {
            bf16x8 af[4], bfr[2];
            for (int i = 0; i < 4; ++i)
                af[i] = *(const bf16x8*)(&Asm[cur][(wm + i * 16 + r16) * 64 + h * 32 + quad * 8]);
            for (int j = 0; j < 2; ++j)
                bfr[j] = *(const bf16x8*)(&Bsm[cur][(wn + j * 16 + r16) * 64 + h * 32 + quad * 8]);
            for (int i = 0; i < 4; ++i)
                for (int j = 0; j < 2; ++j)
                    acc[i][j] = MFMA_BF16(af[i], bfr[j], acc[i][j]);
        }
        __syncthreads();
    }
    for (int i = 0; i < 4; ++i)
        for (int j = 0; j < 2; ++j)
            for (int e = 0; e < 4; ++e) {
                int m = m0 + wm + i * 16 + quad * 4 + e;
                int n = n0 + wn + j * 16 + r16;
                out[(size_t)m * DIM + n] = acc[i][j][e] + bias[n] + resid[(size_t)m * DIM + n];
            }
}

// ---------------------------------------------------------------------------
extern "C" void kernel_launch(void* const* d_in, const int* in_sizes, int n_in,
                              void* d_out, int out_size, void* d_ws, size_t ws_size,
                              hipStream_t stream) {
    const float* x     = (const float*)d_in[0];
    const float* w_qkv = (const float*)d_in[1];
    const float* b_qkv = (const float*)d_in[2];
    const float* w_out = (const float*)d_in[3];
    const float* b_out = (const float*)d_in[4];
    const float* gamma = (const float*)d_in[5];
    const float* ln_b  = (const float*)d_in[6];
    const float* beta  = (const float*)d_in[7];
    float* out = (float*)d_out;

    char* ws = (char*)d_ws;
    const size_t MB = 1u << 20;
    unsigned short* xn    = (unsigned short*)(ws);            // 8 MB (reused as ctx)
    unsigned short* wqkvT = (unsigned short*)(ws + 8 * MB);   // 6 MB
    unsigned short* woutT = (unsigned short*)(ws + 14 * MB);  // 2 MB
    unsigned short* qb    = (unsigned short*)(ws + 16 * MB);  // 8 MB
    unsigned short* kb    = (unsigned short*)(ws + 24 * MB);  // 8 MB
    unsigned short* vTb   = (unsigned short*)(ws + 32 * MB);  // 8 MB
    float* logt_g         = (float*)(ws + 40 * MB);           // 8 KB
    unsigned short* ctx   = xn;  // xn dead after qkv_gemm; safe alias (stream-ordered)

    prep_kernel<<<8196, 256, 0, stream>>>(w_qkv, wqkvT, w_out, woutT, x, gamma, ln_b, xn,
                                          beta, logt_g);
    qkv_gemm<<<256, 512, 0, stream>>>(xn, wqkvT, b_qkv, qb, kb, vTb);
    attn_kernel<<<dim3(SEQ / 128, 32), 512, 0, stream>>>(qb, kb, vTb, logt_g, ctx);
    out_gemm<<<dim3(16, 32), 256, 0, stream>>>(ctx, woutT, b_out, x, out);
}